// Round 5
// baseline (37.250 us; speedup 1.0000x reference)
//
#include <hip/hip_runtime.h>

// out[n,p] = sum_{k=0..7} X[n, p+k] * W[p*8 + k] + b[p],  X zero-padded past P.
// N=1024, P=20000, K=8, LF=1. fp32.
//
// Round-4 lesson: LDS-staged W == strided W (35 vs 37 us) -> W access mode was
// not the limiter; both variants are latency/occupancy-bound (R4's 33.8KB LDS
// caps 16 waves/CU). Fix: transpose W -> Wt[k][P] in d_ws (one tiny kernel).
// Per-thread W becomes 8 coalesced float4 loads, no LDS anywhere -> occupancy
// capped only by VGPR; W reloads (if compiler remats) are coalesced L1 hits.

constexpr int N  = 1024;
constexpr int P  = 20000;
constexpr int K  = 8;
constexpr int P4 = P / 4;              // 5000 column-groups of 4
constexpr int COLS_PADDED = 5120;      // pad to whole blocks
constexpr int NCHUNKS = 128;           // row-chunks
constexpr int ROWS = N / NCHUNKS;      // 8 rows per thread

// ---- one-time W transpose: W[p][k] -> Wt[k][p] (640KB in d_ws) ----
__global__ __launch_bounds__(256)
void transpose_w(const float* __restrict__ W, float* __restrict__ Wt) {
    int p = blockIdx.x * blockDim.x + threadIdx.x;
    if (p >= P) return;
    float4 a = *reinterpret_cast<const float4*>(W + (size_t)p * K);
    float4 c = *reinterpret_cast<const float4*>(W + (size_t)p * K + 4);
    Wt[0 * P + p] = a.x; Wt[1 * P + p] = a.y;
    Wt[2 * P + p] = a.z; Wt[3 * P + p] = a.w;
    Wt[4 * P + p] = c.x; Wt[5 * P + p] = c.y;
    Wt[6 * P + p] = c.z; Wt[7 * P + p] = c.w;
}

__global__ __launch_bounds__(256, 4)
void local_linear_kernel(const float* __restrict__ X,
                         const float* __restrict__ Wt,
                         const float* __restrict__ b,
                         float* __restrict__ out) {
    const int tid   = blockIdx.x * blockDim.x + threadIdx.x;
    const int chunk = tid / COLS_PADDED;
    const int q     = tid - chunk * COLS_PADDED;
    if (q >= P4) return;                     // padding lanes (wave-uniform)
    const int p  = q * 4;
    const int n0 = chunk * ROWS;

    // W for my 4 columns: 8 coalesced float4 loads (lanes have consecutive p)
    float4 wv[8];
    #pragma unroll
    for (int k = 0; k < K; ++k)
        wv[k] = *reinterpret_cast<const float4*>(Wt + (size_t)k * P + p);
    const float4 bv = *reinterpret_cast<const float4*>(b + p);

    const bool interior = (p + 12 <= P);

    #pragma unroll 2
    for (int r = 0; r < ROWS; ++r) {
        const float* xrow = X + (size_t)(n0 + r) * P;

        float xv[12];
        if (interior) {
            float4 a = *reinterpret_cast<const float4*>(xrow + p);
            float4 c = *reinterpret_cast<const float4*>(xrow + p + 4);
            float4 d = *reinterpret_cast<const float4*>(xrow + p + 8);
            xv[0] = a.x; xv[1] = a.y; xv[2]  = a.z; xv[3]  = a.w;
            xv[4] = c.x; xv[5] = c.y; xv[6]  = c.z; xv[7]  = c.w;
            xv[8] = d.x; xv[9] = d.y; xv[10] = d.z; xv[11] = d.w;
        } else {
            #pragma unroll
            for (int i = 0; i < 12; ++i)
                xv[i] = (p + i < P) ? xrow[p + i] : 0.0f;   // matches jnp.pad
        }

        float r0 = bv.x, r1 = bv.y, r2 = bv.z, r3 = bv.w;
        #pragma unroll
        for (int k = 0; k < K; ++k) {
            r0 += xv[k + 0] * wv[k].x;
            r1 += xv[k + 1] * wv[k].y;
            r2 += xv[k + 2] * wv[k].z;
            r3 += xv[k + 3] * wv[k].w;
        }

        float4 o; o.x = r0; o.y = r1; o.z = r2; o.w = r3;
        *reinterpret_cast<float4*>(out + (size_t)(n0 + r) * P + p) = o;
    }
}

// Fallback if ws_size can't hold Wt (640KB): R2-style kernel, strided W once.
__global__ __launch_bounds__(256)
void local_linear_fallback(const float* __restrict__ X,
                           const float* __restrict__ W,
                           const float* __restrict__ b,
                           float* __restrict__ out) {
    const int tid   = blockIdx.x * blockDim.x + threadIdx.x;
    const int chunk = tid / COLS_PADDED;
    const int q     = tid - chunk * COLS_PADDED;
    if (q >= P4) return;
    const int p  = q * 4;
    const int n0 = chunk * ROWS;

    const float* wp = W + (size_t)p * K;
    float wv[32];
    #pragma unroll
    for (int i = 0; i < 8; ++i) {
        float4 w4 = *reinterpret_cast<const float4*>(wp + i * 4);
        wv[i*4+0] = w4.x; wv[i*4+1] = w4.y; wv[i*4+2] = w4.z; wv[i*4+3] = w4.w;
    }
    const float4 bv = *reinterpret_cast<const float4*>(b + p);
    const bool interior = (p + 12 <= P);

    for (int r = 0; r < ROWS; ++r) {
        const float* xrow = X + (size_t)(n0 + r) * P;
        float xv[12];
        if (interior) {
            float4 a = *reinterpret_cast<const float4*>(xrow + p);
            float4 c = *reinterpret_cast<const float4*>(xrow + p + 4);
            float4 d = *reinterpret_cast<const float4*>(xrow + p + 8);
            xv[0]=a.x; xv[1]=a.y; xv[2]=a.z; xv[3]=a.w;
            xv[4]=c.x; xv[5]=c.y; xv[6]=c.z; xv[7]=c.w;
            xv[8]=d.x; xv[9]=d.y; xv[10]=d.z; xv[11]=d.w;
        } else {
            #pragma unroll
            for (int i = 0; i < 12; ++i)
                xv[i] = (p + i < P) ? xrow[p + i] : 0.0f;
        }
        float r0 = bv.x, r1 = bv.y, r2 = bv.z, r3 = bv.w;
        #pragma unroll
        for (int k = 0; k < K; ++k) {
            r0 += xv[0 + k] * wv[0  + k];
            r1 += xv[1 + k] * wv[8  + k];
            r2 += xv[2 + k] * wv[16 + k];
            r3 += xv[3 + k] * wv[24 + k];
        }
        float4 o; o.x = r0; o.y = r1; o.z = r2; o.w = r3;
        *reinterpret_cast<float4*>(out + (size_t)(n0 + r) * P + p) = o;
    }
}

extern "C" void kernel_launch(void* const* d_in, const int* in_sizes, int n_in,
                              void* d_out, int out_size, void* d_ws, size_t ws_size,
                              hipStream_t stream) {
    const float* X = (const float*)d_in[0];
    const float* W = (const float*)d_in[1];
    const float* b = (const float*)d_in[2];
    float* out = (float*)d_out;

    constexpr int total_threads = COLS_PADDED * NCHUNKS;  // 655,360
    constexpr int block = 256;
    constexpr int grid = total_threads / block;           // 2,560 blocks
    constexpr size_t WT_BYTES = (size_t)P * K * sizeof(float);  // 640,000

    if (ws_size >= WT_BYTES) {
        float* Wt = (float*)d_ws;
        transpose_w<<<(P + block - 1) / block, block, 0, stream>>>(W, Wt);
        local_linear_kernel<<<grid, block, 0, stream>>>(X, Wt, b, out);
    } else {
        local_linear_fallback<<<grid, block, 0, stream>>>(X, W, b, out);
    }
}

// Round 7
// 37.012 us; speedup vs baseline: 1.0064x; 1.0064x over previous
//
#include <hip/hip_runtime.h>

// out[n,p] = sum_{k=0..7} X[n, p+k] * W[p*8 + k] + b[p],  X zero-padded past P.
// N=1024, P=20000, K=8, LF=1. fp32.
//
// Round-6 lesson: __builtin_nontemporal_store needs a NATIVE clang vector type,
// not HIP_vector_type<float,4>. Use ext_vector_type(4). Theory unchanged:
// out is write-once -> stream it past L3 so X stays L3-resident across replays.

constexpr int N  = 1024;
constexpr int P  = 20000;
constexpr int K  = 8;
constexpr int P4 = P / 4;              // 5000 column-groups of 4
constexpr int COLS_PADDED = 5120;      // pad to whole blocks
constexpr int NCHUNKS = 128;           // row-chunks
constexpr int ROWS = N / NCHUNKS;      // 8 rows per thread

typedef float float4n __attribute__((ext_vector_type(4)));  // native vec4

// ---- one-time W transpose: W[p][k] -> Wt[k][p] (640KB in d_ws) ----
__global__ __launch_bounds__(256)
void transpose_w(const float* __restrict__ W, float* __restrict__ Wt) {
    int p = blockIdx.x * blockDim.x + threadIdx.x;
    if (p >= P) return;
    float4 a = *reinterpret_cast<const float4*>(W + (size_t)p * K);
    float4 c = *reinterpret_cast<const float4*>(W + (size_t)p * K + 4);
    Wt[0 * P + p] = a.x; Wt[1 * P + p] = a.y;
    Wt[2 * P + p] = a.z; Wt[3 * P + p] = a.w;
    Wt[4 * P + p] = c.x; Wt[5 * P + p] = c.y;
    Wt[6 * P + p] = c.z; Wt[7 * P + p] = c.w;
}

__global__ __launch_bounds__(256, 4)
void local_linear_kernel(const float* __restrict__ X,
                         const float* __restrict__ Wt,
                         const float* __restrict__ b,
                         float* __restrict__ out) {
    const int tid   = blockIdx.x * blockDim.x + threadIdx.x;
    const int chunk = tid / COLS_PADDED;
    const int q     = tid - chunk * COLS_PADDED;
    if (q >= P4) return;                     // padding lanes (wave-uniform)
    const int p  = q * 4;
    const int n0 = chunk * ROWS;

    // W for my 4 columns: 8 coalesced float4 loads (lanes have consecutive p)
    float4 wv[8];
    #pragma unroll
    for (int k = 0; k < K; ++k)
        wv[k] = *reinterpret_cast<const float4*>(Wt + (size_t)k * P + p);
    const float4 bv = *reinterpret_cast<const float4*>(b + p);

    const bool interior = (p + 12 <= P);

    #pragma unroll 4
    for (int r = 0; r < ROWS; ++r) {
        const float* xrow = X + (size_t)(n0 + r) * P;

        float xv[12];
        if (interior) {
            float4 a = *reinterpret_cast<const float4*>(xrow + p);
            float4 c = *reinterpret_cast<const float4*>(xrow + p + 4);
            float4 d = *reinterpret_cast<const float4*>(xrow + p + 8);
            xv[0] = a.x; xv[1] = a.y; xv[2]  = a.z; xv[3]  = a.w;
            xv[4] = c.x; xv[5] = c.y; xv[6]  = c.z; xv[7]  = c.w;
            xv[8] = d.x; xv[9] = d.y; xv[10] = d.z; xv[11] = d.w;
        } else {
            #pragma unroll
            for (int i = 0; i < 12; ++i)
                xv[i] = (p + i < P) ? xrow[p + i] : 0.0f;   // matches jnp.pad
        }

        float r0 = bv.x, r1 = bv.y, r2 = bv.z, r3 = bv.w;
        #pragma unroll
        for (int k = 0; k < K; ++k) {
            r0 += xv[k + 0] * wv[k].x;
            r1 += xv[k + 1] * wv[k].y;
            r2 += xv[k + 2] * wv[k].z;
            r3 += xv[k + 3] * wv[k].w;
        }

        float4n o; o.x = r0; o.y = r1; o.z = r2; o.w = r3;
        // Streaming store: out is write-once -> don't pollute L3 (keep X hot).
        __builtin_nontemporal_store(
            o, reinterpret_cast<float4n*>(out + (size_t)(n0 + r) * P + p));
    }
}

extern "C" void kernel_launch(void* const* d_in, const int* in_sizes, int n_in,
                              void* d_out, int out_size, void* d_ws, size_t ws_size,
                              hipStream_t stream) {
    const float* X = (const float*)d_in[0];
    const float* W = (const float*)d_in[1];
    const float* b = (const float*)d_in[2];
    float* out = (float*)d_out;

    constexpr int total_threads = COLS_PADDED * NCHUNKS;  // 655,360
    constexpr int block = 256;
    constexpr int grid = total_threads / block;           // 2,560 blocks

    float* Wt = (float*)d_ws;                              // 640KB scratch
    transpose_w<<<(P + block - 1) / block, block, 0, stream>>>(W, Wt);
    local_linear_kernel<<<grid, block, 0, stream>>>(X, Wt, b, out);
}